// Round 9
// baseline (266.589 us; speedup 1.0000x reference)
//
#include <hip/hip_runtime.h>
#include <math.h>

#define Bb 16
#define Nn 2048
#define Ff 2048
#define Ee 128
#define Kk 10
#define S2FC 8              // fact chunks in k_s2t
#define S2F (Ff / S2FC)     // 256 facts per block

typedef __attribute__((ext_vector_type(8))) short short8;
typedef __attribute__((ext_vector_type(4))) float f32x4;

// ---------------- helpers ----------------
__device__ inline float wave_sum(float x) {
    for (int o = 32; o; o >>= 1) x += __shfl_down(x, o);
    return x;  // valid in lane 0
}

// split fp32 -> bf16 hi (truncate) + bf16 lo (truncate of exact remainder)
__device__ inline void bsplit(float x, unsigned short& h, unsigned short& l) {
    unsigned int u = __float_as_uint(x);
    h = (unsigned short)(u >> 16);
    float hf = __uint_as_float(u & 0xFFFF0000u);
    l = (unsigned short)(__float_as_uint(x - hf) >> 16);
}

__device__ inline void atomic_fmax_pos(float* addr, float v) {
    // valid for non-negative floats: bit pattern order == float order
    atomicMax((unsigned int*)addr, __float_as_uint(v));
}

// ---------------- K0: prep = fact pre-split (blocks 0..4095) + hop projections (4096..4127) ----
__global__ __launch_bounds__(256) void k_prep(
    const float* __restrict__ rel, const float* __restrict__ hop_W,
    const float* __restrict__ hop_b, const float* __restrict__ fa1,
    const float* __restrict__ fa2, unsigned short* __restrict__ B0,
    unsigned short* __restrict__ B1, float* __restrict__ h) {
    int bx = blockIdx.x;
    int tid = threadIdx.x;
    if (bx < 4096) {
        int y = bx >> 11, bxi = bx & 2047;
        int oct = tid & 15, fl = tid >> 4;
        int b = bxi >> 7, f = (bxi & 127) * 16 + fl;
        const float* src = (y == 0) ? fa2 : fa1;    // r=0 scans fa2, r=1 scans fa1
        unsigned short* dst = ((y == 0) ? B0 : B1) +
                              (((size_t)b * 16 + oct) * Ff + f) * 16;
        const float* s = src + ((size_t)b * Ff + f) * Ee + oct * 8;
        float4 v0 = *(const float4*)s;
        float4 v1 = *(const float4*)(s + 4);
        float xs[8] = {v0.x, v0.y, v0.z, v0.w, v1.x, v1.y, v1.z, v1.w};
        unsigned short hi[8], lo[8];
#pragma unroll
        for (int j = 0; j < 8; ++j) bsplit(xs[j], hi[j], lo[j]);
        uint4 ph, pl;
        ph.x = (unsigned)hi[0] | ((unsigned)hi[1] << 16);
        ph.y = (unsigned)hi[2] | ((unsigned)hi[3] << 16);
        ph.z = (unsigned)hi[4] | ((unsigned)hi[5] << 16);
        ph.w = (unsigned)hi[6] | ((unsigned)hi[7] << 16);
        pl.x = (unsigned)lo[0] | ((unsigned)lo[1] << 16);
        pl.y = (unsigned)lo[2] | ((unsigned)lo[3] << 16);
        pl.z = (unsigned)lo[4] | ((unsigned)lo[5] << 16);
        pl.w = (unsigned)lo[6] | ((unsigned)lo[7] << 16);
        *(uint4*)dst = ph;
        *(uint4*)(dst + 8) = pl;
    } else {
        // hop projections: h[rj][b][e] = rel[b] @ W[rj] + bias  (32 blocks x 256 outputs)
        int idx = (bx - 4096) * 256 + tid;      // 0..8191
        int rj = idx >> 11;
        int b  = (idx >> 7) & 15;
        int e  = idx & 127;
        const float* W  = hop_W + (size_t)rj * Ee * Ee;
        const float* rb = rel + b * Ee;
        float acc = hop_b[rj * Ee + e];
        for (int q = 0; q < Ee; ++q) acc += rb[q] * W[q * Ee + e];
        h[((size_t)rj * Bb + b) * Ee + e] = acc;
    }
}

// ---------------- K3: per-fact distances; 128 facts/block, 256 blocks (1/CU fill) ----------
__global__ __launch_bounds__(128) void k_facts(
    const float* __restrict__ rel, const float* __restrict__ arg1,
    const float* __restrict__ arg2, const float* __restrict__ frel,
    const float* __restrict__ fa1, const float* __restrict__ fa2,
    const float* __restrict__ h, const int* __restrict__ nb_facts,
    float* __restrict__ c0, float* __restrict__ c1,
    float* __restrict__ s2b0, float* __restrict__ s2b1,
    float* __restrict__ out) {
    int fc = blockIdx.x, b = blockIdx.y;
    int tid = threadIdx.x;             // block = 128
    __shared__ float q[7][Ee];         // rel, arg1, arg2, h10, h11, h20, h21
    __shared__ float bred[2];
    q[0][tid] = rel[b * Ee + tid];
    q[1][tid] = arg1[b * Ee + tid];
    q[2][tid] = arg2[b * Ee + tid];
    q[3][tid] = h[((size_t)0 * Bb + b) * Ee + tid];   // h1 r=0
    q[4][tid] = h[((size_t)2 * Bb + b) * Ee + tid];   // h1 r=1
    q[5][tid] = h[((size_t)1 * Bb + b) * Ee + tid];   // h2 r=0
    q[6][tid] = h[((size_t)3 * Bb + b) * Ee + tid];   // h2 r=1
    __syncthreads();

    int f = fc * 128 + tid;
    const float* pr = frel + ((size_t)b * Ff + f) * Ee;
    const float* p1 = fa1 + ((size_t)b * Ff + f) * Ee;
    const float* p2 = fa2 + ((size_t)b * Ff + f) * Ee;
    float d_rr = 0, d_a11 = 0, d_a22 = 0, d_h10 = 0, d_h11 = 0, d_h20 = 0, d_h21 = 0;
    float d_a12 = 0, d_a21 = 0, n1 = 0, n2 = 0;
#pragma unroll 8
    for (int e0 = 0; e0 < Ee; e0 += 4) {
        float4 vr4 = *(const float4*)(pr + e0);
        float4 v14 = *(const float4*)(p1 + e0);
        float4 v24 = *(const float4*)(p2 + e0);
        const float* vrp = (const float*)&vr4;
        const float* v1p = (const float*)&v14;
        const float* v2p = (const float*)&v24;
#pragma unroll
        for (int j = 0; j < 4; ++j) {
            int e = e0 + j;
            float fr = vrp[j], f1 = v1p[j], f2 = v2p[j];
            float t;
            t = q[0][e] - fr; d_rr  += t * t;
            t = q[1][e] - f1; d_a11 += t * t;
            t = q[2][e] - f2; d_a22 += t * t;
            t = q[3][e] - fr; d_h10 += t * t;
            t = q[4][e] - fr; d_h11 += t * t;
            t = q[5][e] - fr; d_h20 += t * t;
            t = q[6][e] - fr; d_h21 += t * t;
            t = q[1][e] - f2; d_a12 += t * t;
            t = q[2][e] - f1; d_a21 += t * t;
            n1 += f1 * f1; n2 += f2 * f2;
        }
    }
    bool valid = f < nb_facts[b];
    const float NI = -INFINITY;
    size_t o = (size_t)b * Ff + f;
    c0[o]   = valid ? (-0.5f * (d_h10 + d_a11 + n2)) : NI;
    c1[o]   = valid ? (-0.5f * (d_h11 + d_a12 + n1)) : NI;
    s2b0[o] = valid ? (-0.5f * (d_h20 + d_a22)) : NI;
    s2b1[o] = valid ? (-0.5f * (d_h21 + d_a21)) : NI;
    // scores_0: block-level max of lsc, ONE atomic per block
    float lsc = valid ? (-0.5f * (d_rr + d_a11 + d_a22)) : NI;
    for (int m = 32; m; m >>= 1) lsc = fmaxf(lsc, __shfl_down(lsc, m));
    if ((tid & 63) == 0) bred[tid >> 6] = lsc;
    __syncthreads();
    if (tid == 0) atomic_fmax_pos(out + b, expf(fmaxf(bred[0], bred[1])));
}

// ---------------- K4: fused bias+max GEMM (R5-best shape, no swizzle, inline norms) ----
#define BMs 128

__global__ __launch_bounds__(256, 2) void k_spmax_mfma(
    const float* __restrict__ ent, const unsigned short* __restrict__ B0,
    const unsigned short* __restrict__ B1, const float* __restrict__ c0,
    const float* __restrict__ c1, const int* __restrict__ nb_entities,
    float* __restrict__ sp0, float* __restrict__ sp1) {
    int nblk = blockIdx.x, b = blockIdx.y, r = blockIdx.z;   // natural mapping (no swizzle)
    const unsigned short* Bt = (r == 0) ? B0 : B1;
    const float* cb = ((r == 0) ? c0 : c1) + (size_t)b * Ff;
    float* sp = ((r == 0) ? sp0 : sp1) + (size_t)b * Nn;

    __shared__ unsigned short alds[2 * 4 * 4 * 64 * 8];   // 32KB A-lo fragments
    __shared__ float normsh[BMs];

    int tid = threadIdx.x;
    int wave = tid >> 6, lane = tid & 63;
    int wm = wave >> 1, wn = wave & 1;
    int lane15 = lane & 15, quad = lane >> 4;

    // ---- A-hi fragments in registers; A-lo to LDS; entity norms inline ----
    short8 ah[4][4];
    {
        const float* abase = ent + ((size_t)b * Nn + (size_t)nblk * BMs + wm * 64) * Ee;
#pragma unroll
        for (int i = 0; i < 4; ++i) {
            float sq = 0.f;
#pragma unroll
            for (int ks = 0; ks < 4; ++ks) {
                const float* p = abase + (size_t)(i * 16 + lane15) * Ee + ks * 32 + quad * 8;
                float4 v0 = *(const float4*)p;
                float4 v1 = *(const float4*)(p + 4);
                float xs[8] = {v0.x, v0.y, v0.z, v0.w, v1.x, v1.y, v1.z, v1.w};
                short8 hi8, lo8;
#pragma unroll
                for (int j = 0; j < 8; ++j) {
                    unsigned short hh, ll;
                    bsplit(xs[j], hh, ll);
                    hi8[j] = (short)hh;
                    lo8[j] = (short)ll;
                    sq += xs[j] * xs[j];
                }
                ah[i][ks] = hi8;
                if (wn == 0)
                    *(short8*)&alds[(((wm * 4 + i) * 4 + ks) * 64 + lane) * 8] = lo8;
            }
            float v = sq;
            v += __shfl_xor(v, 16);
            v += __shfl_xor(v, 32);
            if (wn == 0 && quad == 0) normsh[wm * 64 + i * 16 + lane15] = v;
        }
    }
    __syncthreads();

    const unsigned short* bbase =
        Bt + ((((size_t)b * 16 + quad) * Ff) + wn * 32 + lane15) * 16;

    // prefetch chunk 0's B fragments
    short8 pbh0[4], pbl0[4], pbh1[4], pbl1[4];
#pragma unroll
    for (int ks = 0; ks < 4; ++ks) {
        const unsigned short* p0 = bbase + ((size_t)ks * 4 * Ff) * 16;
        pbh0[ks] = *(const short8*)p0;
        pbl0[ks] = *(const short8*)(p0 + 8);
        pbh1[ks] = *(const short8*)(p0 + 256);
        pbl1[ks] = *(const short8*)(p0 + 264);
    }
    // A-lo double buffer: even ks -> bufA, odd ks -> bufB
    short8 bufA[4], bufB[4];
#pragma unroll
    for (int i = 0; i < 4; ++i)
        bufA[i] = *(short8*)&alds[(((wm * 4 + i) * 4 + 0) * 64 + lane) * 8];

    float mmax[4][4];
#pragma unroll
    for (int i = 0; i < 4; ++i)
#pragma unroll
        for (int rr = 0; rr < 4; ++rr) mmax[i][rr] = -INFINITY;

    for (int c = 0; c < 32; ++c) {
        int f0 = c * 64;
        float cj0 = cb[f0 + wn * 32 + lane15];
        float cj1 = cb[f0 + wn * 32 + 16 + lane15];
        f32x4 acc[4][2];
#pragma unroll
        for (int i = 0; i < 4; ++i) {
            acc[i][0] = (f32x4){cj0, cj0, cj0, cj0};
            acc[i][1] = (f32x4){cj1, cj1, cj1, cj1};
        }
        int fn = ((c + 1) & 31) * 64;

#pragma unroll
        for (int ks = 0; ks < 4; ++ks) {
            short8 bh0 = pbh0[ks], bl0 = pbl0[ks], bh1 = pbh1[ks], bl1 = pbl1[ks];
            // prefetch next chunk's B, same ks
            const unsigned short* p0 = bbase + ((size_t)ks * 4 * Ff + fn) * 16;
            pbh0[ks] = *(const short8*)p0;
            pbl0[ks] = *(const short8*)(p0 + 8);
            pbh1[ks] = *(const short8*)(p0 + 256);
            pbl1[ks] = *(const short8*)(p0 + 264);
            // A-lo: use cur buffer, prefetch next ks into other buffer
            short8* cur = (ks & 1) ? bufB : bufA;
            short8* nxt = (ks & 1) ? bufA : bufB;
            int nks = (ks + 1) & 3;
#pragma unroll
            for (int i = 0; i < 4; ++i)
                nxt[i] = *(short8*)&alds[(((wm * 4 + i) * 4 + nks) * 64 + lane) * 8];
#pragma unroll
            for (int i = 0; i < 4; ++i) {
                acc[i][0] = __builtin_amdgcn_mfma_f32_16x16x32_bf16(ah[i][ks], bh0, acc[i][0], 0, 0, 0);
                acc[i][0] = __builtin_amdgcn_mfma_f32_16x16x32_bf16(cur[i],    bh0, acc[i][0], 0, 0, 0);
                acc[i][0] = __builtin_amdgcn_mfma_f32_16x16x32_bf16(ah[i][ks], bl0, acc[i][0], 0, 0, 0);
                acc[i][1] = __builtin_amdgcn_mfma_f32_16x16x32_bf16(ah[i][ks], bh1, acc[i][1], 0, 0, 0);
                acc[i][1] = __builtin_amdgcn_mfma_f32_16x16x32_bf16(cur[i],    bh1, acc[i][1], 0, 0, 0);
                acc[i][1] = __builtin_amdgcn_mfma_f32_16x16x32_bf16(ah[i][ks], bl1, acc[i][1], 0, 0, 0);
            }
        }

#pragma unroll
        for (int j = 0; j < 2; ++j)
#pragma unroll
            for (int i = 0; i < 4; ++i)
#pragma unroll
                for (int rr = 0; rr < 4; ++rr)
                    mmax[i][rr] = fmaxf(mmax[i][rr], acc[i][j][rr]);
    }

    // ---- reduce across 16 lane15 columns in-wave, then across wn via LDS (reuse alds) ----
    __syncthreads();
    float* red = (float*)alds;   // [128][2]
#pragma unroll
    for (int i = 0; i < 4; ++i)
#pragma unroll
        for (int rr = 0; rr < 4; ++rr) {
            float v = mmax[i][rr];
#pragma unroll
            for (int m = 1; m < 16; m <<= 1) v = fmaxf(v, __shfl_xor(v, m));
            if (lane15 == 0) red[(wm * 64 + i * 16 + quad * 4 + rr) * 2 + wn] = v;
        }
    __syncthreads();
    if (tid < BMs) {
        float m = fmaxf(red[tid * 2], red[tid * 2 + 1]);
        int n = nblk * BMs + tid;
        float v = (n < nb_entities[b]) ? expf(m - 0.5f * normsh[tid]) : 0.0f;
        sp[n] = v;
    }
}

// ---------------- K6: tail = in-block topk (wave 0) + second-hop rescore + ONE atomic/block ----
__global__ __launch_bounds__(256) void k_s2t(
    const float* __restrict__ ent, const float* __restrict__ fa1,
    const float* __restrict__ fa2, const float* __restrict__ s2b0,
    const float* __restrict__ s2b1, const float* __restrict__ sp0,
    const float* __restrict__ sp1, float* __restrict__ out) {
    int fc = blockIdx.x, b = blockIdx.y, r = blockIdx.z;
    const float* factX = (r == 0) ? fa1 : fa2;   // z compares vs fa1 (r=0) / fa2 (r=1)
    const float* s2b   = ((r == 0) ? s2b0 : s2b1) + (size_t)b * Ff;
    const float* sp    = ((r == 0) ? sp0 : sp1) + (size_t)b * Nn;

    __shared__ float zsc[Kk];
    __shared__ int   zidx[Kk];
    __shared__ float zsh[Kk][Ee];
    __shared__ float znorm[Kk];
    __shared__ float red[4][Kk];
    __shared__ float rules[Kk];

    int tid = threadIdx.x;
    int wv = tid >> 6, lane = tid & 63;

    if (wv == 0) {   // single-wave top-K, jax-stable ties (lowest index wins)
        float v[Nn / 64];
#pragma unroll
        for (int i = 0; i < Nn / 64; ++i) v[i] = sp[i * 64 + lane];
        for (int k = 0; k < Kk; ++k) {
            float best = -INFINITY; int bidx = 0;
#pragma unroll
            for (int i = 0; i < Nn / 64; ++i)
                if (v[i] > best) { best = v[i]; bidx = i * 64 + lane; }
#pragma unroll
            for (int m = 1; m < 64; m <<= 1) {
                float ov = __shfl_xor(best, m);
                int oi = __shfl_xor(bidx, m);
                if (ov > best || (ov == best && oi < bidx)) { best = ov; bidx = oi; }
            }
            if (lane == 0) { zsc[k] = best; zidx[k] = bidx; }
            if ((bidx & 63) == lane) {
                int slot = bidx >> 6;
#pragma unroll
                for (int i = 0; i < Nn / 64; ++i)
                    if (i == slot) v[i] = -INFINITY;
            }
        }
    }
    __syncthreads();
    for (int idx = tid; idx < Kk * Ee; idx += 256) {
        int k = idx >> 7, e = idx & 127;
        zsh[k][e] = ent[((size_t)b * Nn + zidx[k]) * Ee + e];
    }
    __syncthreads();
    if (tid < Kk) {
        float s = 0.f;
        for (int e = 0; e < Ee; ++e) { float v = zsh[tid][e]; s += v * v; }
        znorm[tid] = s;
    }
    __syncthreads();

    int f = fc * S2F + tid;
    const float* fp = factX + ((size_t)b * Ff + f) * Ee;
    float acc[Kk];
#pragma unroll
    for (int k = 0; k < Kk; ++k) acc[k] = 0.f;
    float nf = 0.f;
#pragma unroll 4
    for (int e0 = 0; e0 < Ee; e0 += 4) {
        float4 v = *(const float4*)(fp + e0);
        nf += v.x * v.x + v.y * v.y + v.z * v.z + v.w * v.w;
#pragma unroll
        for (int k = 0; k < Kk; ++k) {
            float4 z = *(const float4*)&zsh[k][e0];
            acc[k] += z.x * v.x + z.y * v.y + z.z * v.z + z.w * v.w;
        }
    }
    float base = s2b[f] - 0.5f * nf;   // -INF for invalid facts
    float sc[Kk];
#pragma unroll
    for (int k = 0; k < Kk; ++k) sc[k] = base + acc[k] - 0.5f * znorm[k];
    for (int o = 32; o; o >>= 1)
#pragma unroll
        for (int k = 0; k < Kk; ++k) sc[k] = fmaxf(sc[k], __shfl_down(sc[k], o));
    if ((tid & 63) == 0)
#pragma unroll
        for (int k = 0; k < Kk; ++k) red[wv][k] = sc[k];
    __syncthreads();
    if (tid < Kk) {
        float m = fmaxf(fmaxf(red[0][tid], red[1][tid]), fmaxf(red[2][tid], red[3][tid]));
        // max_f min(exp(s_f), z) == min(exp(max_f s_f), z)
        rules[tid] = fminf(expf(m), zsc[tid]);
    }
    __syncthreads();
    if (tid == 0) {
        float g = rules[0];
#pragma unroll
        for (int k = 1; k < Kk; ++k) g = fmaxf(g, rules[k]);
        atomic_fmax_pos(out + b, g);   // ONE atomic per block
    }
}

extern "C" void kernel_launch(void* const* d_in, const int* in_sizes, int n_in,
                              void* d_out, int out_size, void* d_ws, size_t ws_size,
                              hipStream_t stream) {
    const float* rel  = (const float*)d_in[0];
    const float* arg1 = (const float*)d_in[1];
    const float* arg2 = (const float*)d_in[2];
    const float* frel = (const float*)d_in[3];
    const float* fa1  = (const float*)d_in[4];
    const float* fa2  = (const float*)d_in[5];
    const float* ent  = (const float*)d_in[6];
    const float* hopW = (const float*)d_in[7];
    const float* hopb = (const float*)d_in[8];
    const int* nb_facts    = (const int*)d_in[9];
    const int* nb_entities = (const int*)d_in[10];
    float* out = (float*)d_out;

    float* ws = (float*)d_ws;
    size_t off = 0;
    float* h        = ws + off; off += 4 * Bb * Ee;
    float* c0       = ws + off; off += (size_t)Bb * Ff;
    float* c1       = ws + off; off += (size_t)Bb * Ff;
    float* s2b0     = ws + off; off += (size_t)Bb * Ff;
    float* s2b1     = ws + off; off += (size_t)Bb * Ff;
    float* sp0      = ws + off; off += (size_t)Bb * Nn;
    float* sp1      = ws + off; off += (size_t)Bb * Nn;
    off = (off + 7) & ~(size_t)7;   // 32B-align the split tensors
    unsigned short* B0 = (unsigned short*)(ws + off); off += (size_t)Bb * 16 * Ff * 8;
    unsigned short* B1 = (unsigned short*)(ws + off); off += (size_t)Bb * 16 * Ff * 8;

    hipMemsetAsync(d_out, 0, (size_t)out_size * sizeof(float), stream);
    k_prep<<<dim3(4096 + 32), 256, 0, stream>>>(rel, hopW, hopb, fa1, fa2, B0, B1, h);
    k_facts<<<dim3(Ff / 128, Bb), 128, 0, stream>>>(rel, arg1, arg2, frel, fa1, fa2, h,
                                                    nb_facts, c0, c1, s2b0, s2b1, out);
    k_spmax_mfma<<<dim3(Nn / BMs, Bb, 2), 256, 0, stream>>>(ent, B0, B1, c0, c1,
                                                            nb_entities, sp0, sp1);
    k_s2t<<<dim3(S2FC, Bb, 2), 256, 0, stream>>>(ent, fa1, fa2, s2b0, s2b1,
                                                 sp0, sp1, out);
}

// Round 10
// 238.794 us; speedup vs baseline: 1.1164x; 1.1164x over previous
//
#include <hip/hip_runtime.h>
#include <math.h>

#define Bb 16
#define Nn 2048
#define Ff 2048
#define Ee 128
#define Kk 10
#define S2FC 8              // fact chunks in k_s2t
#define S2F (Ff / S2FC)     // 256 facts per block

typedef __attribute__((ext_vector_type(8))) short short8;
typedef __attribute__((ext_vector_type(4))) float f32x4;

// ---------------- helpers ----------------
__device__ inline float wave_sum(float x) {
    for (int o = 32; o; o >>= 1) x += __shfl_down(x, o);
    return x;  // valid in lane 0
}

// split fp32 -> bf16 hi (truncate) + bf16 lo (truncate of exact remainder)
__device__ inline void bsplit(float x, unsigned short& h, unsigned short& l) {
    unsigned int u = __float_as_uint(x);
    h = (unsigned short)(u >> 16);
    float hf = __uint_as_float(u & 0xFFFF0000u);
    l = (unsigned short)(__float_as_uint(x - hf) >> 16);
}

__device__ inline void atomic_fmax_pos(float* addr, float v) {
    // valid for non-negative floats: bit pattern order == float order
    atomicMax((unsigned int*)addr, __float_as_uint(v));
}

// ---------------- K0: prep = fact pre-split (0..4095) + hops (4096..4127) + entnorm (4128..) ----
__global__ __launch_bounds__(256) void k_prep(
    const float* __restrict__ rel, const float* __restrict__ hop_W,
    const float* __restrict__ hop_b, const float* __restrict__ fa1,
    const float* __restrict__ fa2, const float* __restrict__ ent,
    unsigned short* __restrict__ B0, unsigned short* __restrict__ B1,
    float* __restrict__ h, float* __restrict__ ent_norm) {
    int bx = blockIdx.x;
    int tid = threadIdx.x;
    if (bx < 4096) {
        int y = bx >> 11, bxi = bx & 2047;
        int oct = tid & 15, fl = tid >> 4;
        int b = bxi >> 7, f = (bxi & 127) * 16 + fl;
        const float* src = (y == 0) ? fa2 : fa1;    // r=0 scans fa2, r=1 scans fa1
        unsigned short* dst = ((y == 0) ? B0 : B1) +
                              (((size_t)b * 16 + oct) * Ff + f) * 16;
        const float* s = src + ((size_t)b * Ff + f) * Ee + oct * 8;
        float4 v0 = *(const float4*)s;
        float4 v1 = *(const float4*)(s + 4);
        float xs[8] = {v0.x, v0.y, v0.z, v0.w, v1.x, v1.y, v1.z, v1.w};
        unsigned short hi[8], lo[8];
#pragma unroll
        for (int j = 0; j < 8; ++j) bsplit(xs[j], hi[j], lo[j]);
        uint4 ph, pl;
        ph.x = (unsigned)hi[0] | ((unsigned)hi[1] << 16);
        ph.y = (unsigned)hi[2] | ((unsigned)hi[3] << 16);
        ph.z = (unsigned)hi[4] | ((unsigned)hi[5] << 16);
        ph.w = (unsigned)hi[6] | ((unsigned)hi[7] << 16);
        pl.x = (unsigned)lo[0] | ((unsigned)lo[1] << 16);
        pl.y = (unsigned)lo[2] | ((unsigned)lo[3] << 16);
        pl.z = (unsigned)lo[4] | ((unsigned)lo[5] << 16);
        pl.w = (unsigned)lo[6] | ((unsigned)lo[7] << 16);
        *(uint4*)dst = ph;
        *(uint4*)(dst + 8) = pl;
    } else if (bx < 4128) {
        // hop projections: h[rj][b][e] = rel[b] @ W[rj] + bias  (32 blocks x 256 outputs)
        int idx = (bx - 4096) * 256 + tid;      // 0..8191
        int rj = idx >> 11;
        int b  = (idx >> 7) & 15;
        int e  = idx & 127;
        const float* W  = hop_W + (size_t)rj * Ee * Ee;
        const float* rb = rel + b * Ee;
        float acc = hop_b[rj * Ee + e];
        for (int q = 0; q < Ee; ++q) acc += rb[q] * W[q * Ee + e];
        h[((size_t)rj * Bb + b) * Ee + e] = acc;
    } else {
        // entity self-norms: 8192 blocks, 4 rows each
        int row  = (bx - 4128) * 4 + (tid >> 6);
        int lane = tid & 63;
        const float* p = ent + (size_t)row * Ee;
        float a = p[lane], c = p[lane + 64];
        float s = wave_sum(a * a + c * c);
        if (lane == 0) ent_norm[row] = s;
    }
}

// ---------------- K3: per-fact distances; 128 facts/block, 256 blocks (1/CU fill) ----------
__global__ __launch_bounds__(128) void k_facts(
    const float* __restrict__ rel, const float* __restrict__ arg1,
    const float* __restrict__ arg2, const float* __restrict__ frel,
    const float* __restrict__ fa1, const float* __restrict__ fa2,
    const float* __restrict__ h, const int* __restrict__ nb_facts,
    float* __restrict__ c0, float* __restrict__ c1,
    float* __restrict__ s2b0, float* __restrict__ s2b1,
    float* __restrict__ out) {
    int fc = blockIdx.x, b = blockIdx.y;
    int tid = threadIdx.x;             // block = 128
    __shared__ float q[7][Ee];         // rel, arg1, arg2, h10, h11, h20, h21
    __shared__ float bred[2];
    q[0][tid] = rel[b * Ee + tid];
    q[1][tid] = arg1[b * Ee + tid];
    q[2][tid] = arg2[b * Ee + tid];
    q[3][tid] = h[((size_t)0 * Bb + b) * Ee + tid];   // h1 r=0
    q[4][tid] = h[((size_t)2 * Bb + b) * Ee + tid];   // h1 r=1
    q[5][tid] = h[((size_t)1 * Bb + b) * Ee + tid];   // h2 r=0
    q[6][tid] = h[((size_t)3 * Bb + b) * Ee + tid];   // h2 r=1
    __syncthreads();

    int f = fc * 128 + tid;
    const float* pr = frel + ((size_t)b * Ff + f) * Ee;
    const float* p1 = fa1 + ((size_t)b * Ff + f) * Ee;
    const float* p2 = fa2 + ((size_t)b * Ff + f) * Ee;
    float d_rr = 0, d_a11 = 0, d_a22 = 0, d_h10 = 0, d_h11 = 0, d_h20 = 0, d_h21 = 0;
    float d_a12 = 0, d_a21 = 0, n1 = 0, n2 = 0;
#pragma unroll 8
    for (int e0 = 0; e0 < Ee; e0 += 4) {
        float4 vr4 = *(const float4*)(pr + e0);
        float4 v14 = *(const float4*)(p1 + e0);
        float4 v24 = *(const float4*)(p2 + e0);
        const float* vrp = (const float*)&vr4;
        const float* v1p = (const float*)&v14;
        const float* v2p = (const float*)&v24;
#pragma unroll
        for (int j = 0; j < 4; ++j) {
            int e = e0 + j;
            float fr = vrp[j], f1 = v1p[j], f2 = v2p[j];
            float t;
            t = q[0][e] - fr; d_rr  += t * t;
            t = q[1][e] - f1; d_a11 += t * t;
            t = q[2][e] - f2; d_a22 += t * t;
            t = q[3][e] - fr; d_h10 += t * t;
            t = q[4][e] - fr; d_h11 += t * t;
            t = q[5][e] - fr; d_h20 += t * t;
            t = q[6][e] - fr; d_h21 += t * t;
            t = q[1][e] - f2; d_a12 += t * t;
            t = q[2][e] - f1; d_a21 += t * t;
            n1 += f1 * f1; n2 += f2 * f2;
        }
    }
    bool valid = f < nb_facts[b];
    const float NI = -INFINITY;
    size_t o = (size_t)b * Ff + f;
    c0[o]   = valid ? (-0.5f * (d_h10 + d_a11 + n2)) : NI;
    c1[o]   = valid ? (-0.5f * (d_h11 + d_a12 + n1)) : NI;
    s2b0[o] = valid ? (-0.5f * (d_h20 + d_a22)) : NI;
    s2b1[o] = valid ? (-0.5f * (d_h21 + d_a21)) : NI;
    // scores_0: block-level max of lsc, ONE atomic per block
    float lsc = valid ? (-0.5f * (d_rr + d_a11 + d_a22)) : NI;
    for (int m = 32; m; m >>= 1) lsc = fmaxf(lsc, __shfl_down(lsc, m));
    if ((tid & 63) == 0) bred[tid >> 6] = lsc;
    __syncthreads();
    if (tid == 0) atomic_fmax_pos(out + b, expf(fmaxf(bred[0], bred[1])));
}

// ---------------- K4: fused bias+max GEMM (exact R4/88µs build) + XCD swizzle only ----------
#define BMs 128

__global__ __launch_bounds__(256, 2) void k_spmax_mfma(
    const float* __restrict__ ent, const unsigned short* __restrict__ B0,
    const unsigned short* __restrict__ B1, const float* __restrict__ c0,
    const float* __restrict__ c1, const float* __restrict__ ent_norm,
    const int* __restrict__ nb_entities, float* __restrict__ sp0,
    float* __restrict__ sp1) {
    // swizzle: 16 blocks sharing one (b,r) B-slice are 32 apart -> same XCD (mod 8)
    int bid = blockIdx.x;
    int br = bid & 31, nblk = bid >> 5;
    int b = br >> 1, r = br & 1;
    const unsigned short* Bt = (r == 0) ? B0 : B1;
    const float* cb = ((r == 0) ? c0 : c1) + (size_t)b * Ff;
    float* sp = ((r == 0) ? sp0 : sp1) + (size_t)b * Nn;

    __shared__ unsigned short alds[2 * 4 * 4 * 64 * 8];   // 32KB A-lo fragments

    int tid = threadIdx.x;
    int wave = tid >> 6, lane = tid & 63;
    int wm = wave >> 1, wn = wave & 1;
    int lane15 = lane & 15, quad = lane >> 4;

    // ---- A-hi fragments in registers; A-lo staged once to LDS ----
    short8 ah[4][4];
    {
        const float* abase = ent + ((size_t)b * Nn + (size_t)nblk * BMs + wm * 64) * Ee;
#pragma unroll
        for (int i = 0; i < 4; ++i)
#pragma unroll
            for (int ks = 0; ks < 4; ++ks) {
                const float* p = abase + (size_t)(i * 16 + lane15) * Ee + ks * 32 + quad * 8;
                float4 v0 = *(const float4*)p;
                float4 v1 = *(const float4*)(p + 4);
                float xs[8] = {v0.x, v0.y, v0.z, v0.w, v1.x, v1.y, v1.z, v1.w};
                short8 hi8, lo8;
#pragma unroll
                for (int j = 0; j < 8; ++j) {
                    unsigned short hh, ll;
                    bsplit(xs[j], hh, ll);
                    hi8[j] = (short)hh;
                    lo8[j] = (short)ll;
                }
                ah[i][ks] = hi8;
                if (wn == 0)
                    *(short8*)&alds[(((wm * 4 + i) * 4 + ks) * 64 + lane) * 8] = lo8;
            }
    }
    __syncthreads();

    // wave-invariant B base: unit (b, oct=ks*4+quad, row=wn*32+lane15)
    const unsigned short* bbase =
        Bt + ((((size_t)b * 16 + quad) * Ff) + wn * 32 + lane15) * 16;

    // prefetch chunk 0's B fragments
    short8 pbh0[4], pbl0[4], pbh1[4], pbl1[4];
#pragma unroll
    for (int ks = 0; ks < 4; ++ks) {
        const unsigned short* p0 = bbase + ((size_t)ks * 4 * Ff) * 16;
        pbh0[ks] = *(const short8*)p0;
        pbl0[ks] = *(const short8*)(p0 + 8);
        pbh1[ks] = *(const short8*)(p0 + 256);
        pbl1[ks] = *(const short8*)(p0 + 264);
    }
    // A-lo double buffer: even ks -> bufA, odd ks -> bufB
    short8 bufA[4], bufB[4];
#pragma unroll
    for (int i = 0; i < 4; ++i)
        bufA[i] = *(short8*)&alds[(((wm * 4 + i) * 4 + 0) * 64 + lane) * 8];

    float mmax[4][4];
#pragma unroll
    for (int i = 0; i < 4; ++i)
#pragma unroll
        for (int rr = 0; rr < 4; ++rr) mmax[i][rr] = -INFINITY;

    for (int c = 0; c < 32; ++c) {
        int f0 = c * 64;
        float cj0 = cb[f0 + wn * 32 + lane15];
        float cj1 = cb[f0 + wn * 32 + 16 + lane15];
        f32x4 acc[4][2];
#pragma unroll
        for (int i = 0; i < 4; ++i) {
            acc[i][0] = (f32x4){cj0, cj0, cj0, cj0};   // bias pre-loaded into accumulator
            acc[i][1] = (f32x4){cj1, cj1, cj1, cj1};
        }
        int fn = ((c + 1) & 31) * 64;   // wraps on last chunk (harmless redundant load)

#pragma unroll
        for (int ks = 0; ks < 4; ++ks) {
            short8 bh0 = pbh0[ks], bl0 = pbl0[ks], bh1 = pbh1[ks], bl1 = pbl1[ks];
            // prefetch next chunk, same ks (stays in flight across this ks's MFMAs)
            const unsigned short* p0 = bbase + ((size_t)ks * 4 * Ff + fn) * 16;
            pbh0[ks] = *(const short8*)p0;
            pbl0[ks] = *(const short8*)(p0 + 8);
            pbh1[ks] = *(const short8*)(p0 + 256);
            pbl1[ks] = *(const short8*)(p0 + 264);
            // A-lo: use cur buffer, prefetch next ks into other buffer
            short8* cur = (ks & 1) ? bufB : bufA;
            short8* nxt = (ks & 1) ? bufA : bufB;
            int nks = (ks + 1) & 3;
#pragma unroll
            for (int i = 0; i < 4; ++i)
                nxt[i] = *(short8*)&alds[(((wm * 4 + i) * 4 + nks) * 64 + lane) * 8];
#pragma unroll
            for (int i = 0; i < 4; ++i) {
                acc[i][0] = __builtin_amdgcn_mfma_f32_16x16x32_bf16(ah[i][ks], bh0, acc[i][0], 0, 0, 0);
                acc[i][0] = __builtin_amdgcn_mfma_f32_16x16x32_bf16(cur[i],    bh0, acc[i][0], 0, 0, 0);
                acc[i][0] = __builtin_amdgcn_mfma_f32_16x16x32_bf16(ah[i][ks], bl0, acc[i][0], 0, 0, 0);
                acc[i][1] = __builtin_amdgcn_mfma_f32_16x16x32_bf16(ah[i][ks], bh1, acc[i][1], 0, 0, 0);
                acc[i][1] = __builtin_amdgcn_mfma_f32_16x16x32_bf16(cur[i],    bh1, acc[i][1], 0, 0, 0);
                acc[i][1] = __builtin_amdgcn_mfma_f32_16x16x32_bf16(ah[i][ks], bl1, acc[i][1], 0, 0, 0);
            }
        }

#pragma unroll
        for (int j = 0; j < 2; ++j)
#pragma unroll
            for (int i = 0; i < 4; ++i)
#pragma unroll
                for (int rr = 0; rr < 4; ++rr)
                    mmax[i][rr] = fmaxf(mmax[i][rr], acc[i][j][rr]);
    }

    // ---- reduce across 16 lane15 columns in-wave, then across wn via LDS (reuse alds) ----
    __syncthreads();
    float* red = (float*)alds;   // [128][2]
#pragma unroll
    for (int i = 0; i < 4; ++i)
#pragma unroll
        for (int rr = 0; rr < 4; ++rr) {
            float v = mmax[i][rr];
#pragma unroll
            for (int m = 1; m < 16; m <<= 1) v = fmaxf(v, __shfl_xor(v, m));
            if (lane15 == 0) red[(wm * 64 + i * 16 + quad * 4 + rr) * 2 + wn] = v;
        }
    __syncthreads();
    if (tid < BMs) {
        float m = fmaxf(red[tid * 2], red[tid * 2 + 1]);
        int n = nblk * BMs + tid;
        float v = (n < nb_entities[b]) ? expf(m - 0.5f * ent_norm[(size_t)b * Nn + n]) : 0.0f;
        sp[n] = v;
    }
}

// ---------------- K6: tail = in-block topk (wave 0) + second-hop rescore + ONE atomic/block ----
__global__ __launch_bounds__(256) void k_s2t(
    const float* __restrict__ ent, const float* __restrict__ fa1,
    const float* __restrict__ fa2, const float* __restrict__ s2b0,
    const float* __restrict__ s2b1, const float* __restrict__ sp0,
    const float* __restrict__ sp1, float* __restrict__ out) {
    int fc = blockIdx.x, b = blockIdx.y, r = blockIdx.z;
    const float* factX = (r == 0) ? fa1 : fa2;   // z compares vs fa1 (r=0) / fa2 (r=1)
    const float* s2b   = ((r == 0) ? s2b0 : s2b1) + (size_t)b * Ff;
    const float* sp    = ((r == 0) ? sp0 : sp1) + (size_t)b * Nn;

    __shared__ float zsc[Kk];
    __shared__ int   zidx[Kk];
    __shared__ float zsh[Kk][Ee];
    __shared__ float znorm[Kk];
    __shared__ float red[4][Kk];
    __shared__ float rules[Kk];

    int tid = threadIdx.x;
    int wv = tid >> 6, lane = tid & 63;

    if (wv == 0) {   // single-wave top-K, jax-stable ties (lowest index wins)
        float v[Nn / 64];
#pragma unroll
        for (int i = 0; i < Nn / 64; ++i) v[i] = sp[i * 64 + lane];
        for (int k = 0; k < Kk; ++k) {
            float best = -INFINITY; int bidx = 0;
#pragma unroll
            for (int i = 0; i < Nn / 64; ++i)
                if (v[i] > best) { best = v[i]; bidx = i * 64 + lane; }
#pragma unroll
            for (int m = 1; m < 64; m <<= 1) {
                float ov = __shfl_xor(best, m);
                int oi = __shfl_xor(bidx, m);
                if (ov > best || (ov == best && oi < bidx)) { best = ov; bidx = oi; }
            }
            if (lane == 0) { zsc[k] = best; zidx[k] = bidx; }
            if ((bidx & 63) == lane) {
                int slot = bidx >> 6;
#pragma unroll
                for (int i = 0; i < Nn / 64; ++i)
                    if (i == slot) v[i] = -INFINITY;
            }
        }
    }
    __syncthreads();
    for (int idx = tid; idx < Kk * Ee; idx += 256) {
        int k = idx >> 7, e = idx & 127;
        zsh[k][e] = ent[((size_t)b * Nn + zidx[k]) * Ee + e];
    }
    __syncthreads();
    if (tid < Kk) {
        float s = 0.f;
        for (int e = 0; e < Ee; ++e) { float v = zsh[tid][e]; s += v * v; }
        znorm[tid] = s;
    }
    __syncthreads();

    int f = fc * S2F + tid;
    const float* fp = factX + ((size_t)b * Ff + f) * Ee;
    float acc[Kk];
#pragma unroll
    for (int k = 0; k < Kk; ++k) acc[k] = 0.f;
    float nf = 0.f;
#pragma unroll 4
    for (int e0 = 0; e0 < Ee; e0 += 4) {
        float4 v = *(const float4*)(fp + e0);
        nf += v.x * v.x + v.y * v.y + v.z * v.z + v.w * v.w;
#pragma unroll
        for (int k = 0; k < Kk; ++k) {
            float4 z = *(const float4*)&zsh[k][e0];
            acc[k] += z.x * v.x + z.y * v.y + z.z * v.z + z.w * v.w;
        }
    }
    float base = s2b[f] - 0.5f * nf;   // -INF for invalid facts
    float sc[Kk];
#pragma unroll
    for (int k = 0; k < Kk; ++k) sc[k] = base + acc[k] - 0.5f * znorm[k];
    for (int o = 32; o; o >>= 1)
#pragma unroll
        for (int k = 0; k < Kk; ++k) sc[k] = fmaxf(sc[k], __shfl_down(sc[k], o));
    if ((tid & 63) == 0)
#pragma unroll
        for (int k = 0; k < Kk; ++k) red[wv][k] = sc[k];
    __syncthreads();
    if (tid < Kk) {
        float m = fmaxf(fmaxf(red[0][tid], red[1][tid]), fmaxf(red[2][tid], red[3][tid]));
        // max_f min(exp(s_f), z) == min(exp(max_f s_f), z)
        rules[tid] = fminf(expf(m), zsc[tid]);
    }
    __syncthreads();
    if (tid == 0) {
        float g = rules[0];
#pragma unroll
        for (int k = 1; k < Kk; ++k) g = fmaxf(g, rules[k]);
        atomic_fmax_pos(out + b, g);   // ONE atomic per block
    }
}

extern "C" void kernel_launch(void* const* d_in, const int* in_sizes, int n_in,
                              void* d_out, int out_size, void* d_ws, size_t ws_size,
                              hipStream_t stream) {
    const float* rel  = (const float*)d_in[0];
    const float* arg1 = (const float*)d_in[1];
    const float* arg2 = (const float*)d_in[2];
    const float* frel = (const float*)d_in[3];
    const float* fa1  = (const float*)d_in[4];
    const float* fa2  = (const float*)d_in[5];
    const float* ent  = (const float*)d_in[6];
    const float* hopW = (const float*)d_in[7];
    const float* hopb = (const float*)d_in[8];
    const int* nb_facts    = (const int*)d_in[9];
    const int* nb_entities = (const int*)d_in[10];
    float* out = (float*)d_out;

    float* ws = (float*)d_ws;
    size_t off = 0;
    float* h        = ws + off; off += 4 * Bb * Ee;
    float* c0       = ws + off; off += (size_t)Bb * Ff;
    float* c1       = ws + off; off += (size_t)Bb * Ff;
    float* s2b0     = ws + off; off += (size_t)Bb * Ff;
    float* s2b1     = ws + off; off += (size_t)Bb * Ff;
    float* sp0      = ws + off; off += (size_t)Bb * Nn;
    float* sp1      = ws + off; off += (size_t)Bb * Nn;
    float* ent_norm = ws + off; off += (size_t)Bb * Nn;
    off = (off + 7) & ~(size_t)7;   // 32B-align the split tensors
    unsigned short* B0 = (unsigned short*)(ws + off); off += (size_t)Bb * 16 * Ff * 8;
    unsigned short* B1 = (unsigned short*)(ws + off); off += (size_t)Bb * 16 * Ff * 8;

    hipMemsetAsync(d_out, 0, (size_t)out_size * sizeof(float), stream);
    k_prep<<<dim3(4096 + 32 + Bb * Nn / 4), 256, 0, stream>>>(
        rel, hopW, hopb, fa1, fa2, ent, B0, B1, h, ent_norm);
    k_facts<<<dim3(Ff / 128, Bb), 128, 0, stream>>>(rel, arg1, arg2, frel, fa1, fa2, h,
                                                    nb_facts, c0, c1, s2b0, s2b1, out);
    k_spmax_mfma<<<dim3(512), 256, 0, stream>>>(ent, B0, B1, c0, c1, ent_norm,
                                                nb_entities, sp0, sp1);
    k_s2t<<<dim3(S2FC, Bb, 2), 256, 0, stream>>>(ent, fa1, fa2, s2b0, s2b1,
                                                 sp0, sp1, out);
}

// Round 11
// 232.687 us; speedup vs baseline: 1.1457x; 1.0262x over previous
//
#include <hip/hip_runtime.h>
#include <math.h>

#define Bb 16
#define Nn 2048
#define Ff 2048
#define Ee 128
#define Kk 10
#define S2FC 8              // fact chunks in k_s2t
#define S2F (Ff / S2FC)     // 256 facts per block

typedef __attribute__((ext_vector_type(8))) short short8;
typedef __attribute__((ext_vector_type(4))) float f32x4;

// ---------------- helpers ----------------
__device__ inline float wave_sum(float x) {
    for (int o = 32; o; o >>= 1) x += __shfl_down(x, o);
    return x;  // valid in lane 0
}

// split fp32 -> bf16 hi (truncate) + bf16 lo (truncate of exact remainder)
__device__ inline void bsplit(float x, unsigned short& h, unsigned short& l) {
    unsigned int u = __float_as_uint(x);
    h = (unsigned short)(u >> 16);
    float hf = __uint_as_float(u & 0xFFFF0000u);
    l = (unsigned short)(__float_as_uint(x - hf) >> 16);
}

__device__ inline void atomic_fmax_pos(float* addr, float v) {
    // valid for non-negative floats: bit pattern order == float order
    atomicMax((unsigned int*)addr, __float_as_uint(v));
}

// ---------------- K1: pfe = facts(+inline hops) [0..127] + fact pre-split [128..4223]
//                       + entity norms [4224..12415] ----------------
__global__ __launch_bounds__(256) void k_pfe(
    const float* __restrict__ rel, const float* __restrict__ arg1,
    const float* __restrict__ arg2, const float* __restrict__ frel,
    const float* __restrict__ fa1, const float* __restrict__ fa2,
    const float* __restrict__ ent, const float* __restrict__ hop_W,
    const float* __restrict__ hop_b, const int* __restrict__ nb_facts,
    unsigned short* __restrict__ B0, unsigned short* __restrict__ B1,
    float* __restrict__ ent_norm, float* __restrict__ c0, float* __restrict__ c1,
    float* __restrict__ s2b0, float* __restrict__ s2b1, float* __restrict__ out) {
    int bx = blockIdx.x;
    int tid = threadIdx.x;
    if (bx < 128) {
        // ---- facts: 256 facts/block, hops recomputed per block (identical fp order) ----
        int fcb = bx & 7, b = bx >> 3;
        __shared__ float q[7][Ee];     // rel, arg1, arg2, h10(rj0), h11(rj2), h20(rj1), h21(rj3)
        __shared__ float bred[4];
        if (tid < 128) {
            q[0][tid] = rel[b * Ee + tid];
            q[1][tid] = arg1[b * Ee + tid];
            q[2][tid] = arg2[b * Ee + tid];
        }
        __syncthreads();
        {   // hop projections: threads 0-127 do rj0,rj1; threads 128-255 do rj2,rj3
            int e = tid & 127, hf = tid >> 7;
            const float* W0 = hop_W + (size_t)(hf * 2) * Ee * Ee;
            const float* W1 = W0 + (size_t)Ee * Ee;
            float a0 = hop_b[(hf * 2) * Ee + e];
            float a1 = hop_b[(hf * 2 + 1) * Ee + e];
            for (int qq = 0; qq < Ee; ++qq) {
                float rq = q[0][qq];
                a0 += rq * W0[qq * Ee + e];
                a1 += rq * W1[qq * Ee + e];
            }
            q[3 + hf][e] = a0;   // hf0 -> q3 (h1 r0), hf1 -> q4 (h1 r1)
            q[5 + hf][e] = a1;   // hf0 -> q5 (h2 r0), hf1 -> q6 (h2 r1)
        }
        __syncthreads();

        int f = fcb * 256 + tid;
        const float* pr = frel + ((size_t)b * Ff + f) * Ee;
        const float* p1 = fa1 + ((size_t)b * Ff + f) * Ee;
        const float* p2 = fa2 + ((size_t)b * Ff + f) * Ee;
        float d_rr = 0, d_a11 = 0, d_a22 = 0, d_h10 = 0, d_h11 = 0, d_h20 = 0, d_h21 = 0;
        float d_a12 = 0, d_a21 = 0, n1 = 0, n2 = 0;
#pragma unroll 8
        for (int e0 = 0; e0 < Ee; e0 += 4) {
            float4 vr4 = *(const float4*)(pr + e0);
            float4 v14 = *(const float4*)(p1 + e0);
            float4 v24 = *(const float4*)(p2 + e0);
            const float* vrp = (const float*)&vr4;
            const float* v1p = (const float*)&v14;
            const float* v2p = (const float*)&v24;
#pragma unroll
            for (int j = 0; j < 4; ++j) {
                int e = e0 + j;
                float fr = vrp[j], f1 = v1p[j], f2 = v2p[j];
                float t;
                t = q[0][e] - fr; d_rr  += t * t;
                t = q[1][e] - f1; d_a11 += t * t;
                t = q[2][e] - f2; d_a22 += t * t;
                t = q[3][e] - fr; d_h10 += t * t;
                t = q[4][e] - fr; d_h11 += t * t;
                t = q[5][e] - fr; d_h20 += t * t;
                t = q[6][e] - fr; d_h21 += t * t;
                t = q[1][e] - f2; d_a12 += t * t;
                t = q[2][e] - f1; d_a21 += t * t;
                n1 += f1 * f1; n2 += f2 * f2;
            }
        }
        bool valid = f < nb_facts[b];
        const float NI = -INFINITY;
        size_t o = (size_t)b * Ff + f;
        c0[o]   = valid ? (-0.5f * (d_h10 + d_a11 + n2)) : NI;
        c1[o]   = valid ? (-0.5f * (d_h11 + d_a12 + n1)) : NI;
        s2b0[o] = valid ? (-0.5f * (d_h20 + d_a22)) : NI;
        s2b1[o] = valid ? (-0.5f * (d_h21 + d_a21)) : NI;
        // scores_0: block-level max of lsc, ONE atomic per block
        float lsc = valid ? (-0.5f * (d_rr + d_a11 + d_a22)) : NI;
        for (int m = 32; m; m >>= 1) lsc = fmaxf(lsc, __shfl_down(lsc, m));
        if ((tid & 63) == 0) bred[tid >> 6] = lsc;
        __syncthreads();
        if (tid == 0) {
            float m = fmaxf(fmaxf(bred[0], bred[1]), fmaxf(bred[2], bred[3]));
            atomic_fmax_pos(out + b, expf(m));
        }
    } else if (bx < 128 + 4096) {
        // ---- fact pre-split into MFMA-fragment order ----
        int bxx = bx - 128;
        int y = bxx >> 11, bxi = bxx & 2047;
        int oct = tid & 15, fl = tid >> 4;
        int b = bxi >> 7, f = (bxi & 127) * 16 + fl;
        const float* src = (y == 0) ? fa2 : fa1;    // r=0 scans fa2, r=1 scans fa1
        unsigned short* dst = ((y == 0) ? B0 : B1) +
                              (((size_t)b * 16 + oct) * Ff + f) * 16;
        const float* s = src + ((size_t)b * Ff + f) * Ee + oct * 8;
        float4 v0 = *(const float4*)s;
        float4 v1 = *(const float4*)(s + 4);
        float xs[8] = {v0.x, v0.y, v0.z, v0.w, v1.x, v1.y, v1.z, v1.w};
        unsigned short hi[8], lo[8];
#pragma unroll
        for (int j = 0; j < 8; ++j) bsplit(xs[j], hi[j], lo[j]);
        uint4 ph, pl;
        ph.x = (unsigned)hi[0] | ((unsigned)hi[1] << 16);
        ph.y = (unsigned)hi[2] | ((unsigned)hi[3] << 16);
        ph.z = (unsigned)hi[4] | ((unsigned)hi[5] << 16);
        ph.w = (unsigned)hi[6] | ((unsigned)hi[7] << 16);
        pl.x = (unsigned)lo[0] | ((unsigned)lo[1] << 16);
        pl.y = (unsigned)lo[2] | ((unsigned)lo[3] << 16);
        pl.z = (unsigned)lo[4] | ((unsigned)lo[5] << 16);
        pl.w = (unsigned)lo[6] | ((unsigned)lo[7] << 16);
        *(uint4*)dst = ph;
        *(uint4*)(dst + 8) = pl;
    } else {
        // ---- entity self-norms: 8192 blocks, 4 rows each ----
        int row  = (bx - (128 + 4096)) * 4 + (tid >> 6);
        int lane = tid & 63;
        const float* p = ent + (size_t)row * Ee;
        float a = p[lane], c = p[lane + 64];
        float s = wave_sum(a * a + c * c);
        if (lane == 0) ent_norm[row] = s;
    }
}

// ---------------- K2: fused bias+max GEMM (R9 verbatim: R4 build + XCD swizzle) ----------
#define BMs 128

__global__ __launch_bounds__(256, 2) void k_spmax_mfma(
    const float* __restrict__ ent, const unsigned short* __restrict__ B0,
    const unsigned short* __restrict__ B1, const float* __restrict__ c0,
    const float* __restrict__ c1, const float* __restrict__ ent_norm,
    const int* __restrict__ nb_entities, float* __restrict__ sp0,
    float* __restrict__ sp1) {
    // swizzle: 16 blocks sharing one (b,r) B-slice are 32 apart -> same XCD (mod 8)
    int bid = blockIdx.x;
    int br = bid & 31, nblk = bid >> 5;
    int b = br >> 1, r = br & 1;
    const unsigned short* Bt = (r == 0) ? B0 : B1;
    const float* cb = ((r == 0) ? c0 : c1) + (size_t)b * Ff;
    float* sp = ((r == 0) ? sp0 : sp1) + (size_t)b * Nn;

    __shared__ unsigned short alds[2 * 4 * 4 * 64 * 8];   // 32KB A-lo fragments

    int tid = threadIdx.x;
    int wave = tid >> 6, lane = tid & 63;
    int wm = wave >> 1, wn = wave & 1;
    int lane15 = lane & 15, quad = lane >> 4;

    // ---- A-hi fragments in registers; A-lo staged once to LDS ----
    short8 ah[4][4];
    {
        const float* abase = ent + ((size_t)b * Nn + (size_t)nblk * BMs + wm * 64) * Ee;
#pragma unroll
        for (int i = 0; i < 4; ++i)
#pragma unroll
            for (int ks = 0; ks < 4; ++ks) {
                const float* p = abase + (size_t)(i * 16 + lane15) * Ee + ks * 32 + quad * 8;
                float4 v0 = *(const float4*)p;
                float4 v1 = *(const float4*)(p + 4);
                float xs[8] = {v0.x, v0.y, v0.z, v0.w, v1.x, v1.y, v1.z, v1.w};
                short8 hi8, lo8;
#pragma unroll
                for (int j = 0; j < 8; ++j) {
                    unsigned short hh, ll;
                    bsplit(xs[j], hh, ll);
                    hi8[j] = (short)hh;
                    lo8[j] = (short)ll;
                }
                ah[i][ks] = hi8;
                if (wn == 0)
                    *(short8*)&alds[(((wm * 4 + i) * 4 + ks) * 64 + lane) * 8] = lo8;
            }
    }
    __syncthreads();

    // wave-invariant B base: unit (b, oct=ks*4+quad, row=wn*32+lane15)
    const unsigned short* bbase =
        Bt + ((((size_t)b * 16 + quad) * Ff) + wn * 32 + lane15) * 16;

    // prefetch chunk 0's B fragments
    short8 pbh0[4], pbl0[4], pbh1[4], pbl1[4];
#pragma unroll
    for (int ks = 0; ks < 4; ++ks) {
        const unsigned short* p0 = bbase + ((size_t)ks * 4 * Ff) * 16;
        pbh0[ks] = *(const short8*)p0;
        pbl0[ks] = *(const short8*)(p0 + 8);
        pbh1[ks] = *(const short8*)(p0 + 256);
        pbl1[ks] = *(const short8*)(p0 + 264);
    }
    // A-lo double buffer: even ks -> bufA, odd ks -> bufB
    short8 bufA[4], bufB[4];
#pragma unroll
    for (int i = 0; i < 4; ++i)
        bufA[i] = *(short8*)&alds[(((wm * 4 + i) * 4 + 0) * 64 + lane) * 8];

    float mmax[4][4];
#pragma unroll
    for (int i = 0; i < 4; ++i)
#pragma unroll
        for (int rr = 0; rr < 4; ++rr) mmax[i][rr] = -INFINITY;

    for (int c = 0; c < 32; ++c) {
        int f0 = c * 64;
        float cj0 = cb[f0 + wn * 32 + lane15];
        float cj1 = cb[f0 + wn * 32 + 16 + lane15];
        f32x4 acc[4][2];
#pragma unroll
        for (int i = 0; i < 4; ++i) {
            acc[i][0] = (f32x4){cj0, cj0, cj0, cj0};   // bias pre-loaded into accumulator
            acc[i][1] = (f32x4){cj1, cj1, cj1, cj1};
        }
        int fn = ((c + 1) & 31) * 64;   // wraps on last chunk (harmless redundant load)

#pragma unroll
        for (int ks = 0; ks < 4; ++ks) {
            short8 bh0 = pbh0[ks], bl0 = pbl0[ks], bh1 = pbh1[ks], bl1 = pbl1[ks];
            // prefetch next chunk, same ks (stays in flight across this ks's MFMAs)
            const unsigned short* p0 = bbase + ((size_t)ks * 4 * Ff + fn) * 16;
            pbh0[ks] = *(const short8*)p0;
            pbl0[ks] = *(const short8*)(p0 + 8);
            pbh1[ks] = *(const short8*)(p0 + 256);
            pbl1[ks] = *(const short8*)(p0 + 264);
            // A-lo: use cur buffer, prefetch next ks into other buffer
            short8* cur = (ks & 1) ? bufB : bufA;
            short8* nxt = (ks & 1) ? bufA : bufB;
            int nks = (ks + 1) & 3;
#pragma unroll
            for (int i = 0; i < 4; ++i)
                nxt[i] = *(short8*)&alds[(((wm * 4 + i) * 4 + nks) * 64 + lane) * 8];
#pragma unroll
            for (int i = 0; i < 4; ++i) {
                acc[i][0] = __builtin_amdgcn_mfma_f32_16x16x32_bf16(ah[i][ks], bh0, acc[i][0], 0, 0, 0);
                acc[i][0] = __builtin_amdgcn_mfma_f32_16x16x32_bf16(cur[i],    bh0, acc[i][0], 0, 0, 0);
                acc[i][0] = __builtin_amdgcn_mfma_f32_16x16x32_bf16(ah[i][ks], bl0, acc[i][0], 0, 0, 0);
                acc[i][1] = __builtin_amdgcn_mfma_f32_16x16x32_bf16(ah[i][ks], bh1, acc[i][1], 0, 0, 0);
                acc[i][1] = __builtin_amdgcn_mfma_f32_16x16x32_bf16(cur[i],    bh1, acc[i][1], 0, 0, 0);
                acc[i][1] = __builtin_amdgcn_mfma_f32_16x16x32_bf16(ah[i][ks], bl1, acc[i][1], 0, 0, 0);
            }
        }

#pragma unroll
        for (int j = 0; j < 2; ++j)
#pragma unroll
            for (int i = 0; i < 4; ++i)
#pragma unroll
                for (int rr = 0; rr < 4; ++rr)
                    mmax[i][rr] = fmaxf(mmax[i][rr], acc[i][j][rr]);
    }

    // ---- reduce across 16 lane15 columns in-wave, then across wn via LDS (reuse alds) ----
    __syncthreads();
    float* red = (float*)alds;   // [128][2]
#pragma unroll
    for (int i = 0; i < 4; ++i)
#pragma unroll
        for (int rr = 0; rr < 4; ++rr) {
            float v = mmax[i][rr];
#pragma unroll
            for (int m = 1; m < 16; m <<= 1) v = fmaxf(v, __shfl_xor(v, m));
            if (lane15 == 0) red[(wm * 64 + i * 16 + quad * 4 + rr) * 2 + wn] = v;
        }
    __syncthreads();
    if (tid < BMs) {
        float m = fmaxf(red[tid * 2], red[tid * 2 + 1]);
        int n = nblk * BMs + tid;
        float v = (n < nb_entities[b]) ? expf(m - 0.5f * ent_norm[(size_t)b * Nn + n]) : 0.0f;
        sp[n] = v;
    }
}

// ---------------- K3: tail = in-block topk (wave 0) + second-hop rescore + ONE atomic/block ----
__global__ __launch_bounds__(256) void k_s2t(
    const float* __restrict__ ent, const float* __restrict__ fa1,
    const float* __restrict__ fa2, const float* __restrict__ s2b0,
    const float* __restrict__ s2b1, const float* __restrict__ sp0,
    const float* __restrict__ sp1, float* __restrict__ out) {
    int fc = blockIdx.x, b = blockIdx.y, r = blockIdx.z;
    const float* factX = (r == 0) ? fa1 : fa2;   // z compares vs fa1 (r=0) / fa2 (r=1)
    const float* s2b   = ((r == 0) ? s2b0 : s2b1) + (size_t)b * Ff;
    const float* sp    = ((r == 0) ? sp0 : sp1) + (size_t)b * Nn;

    __shared__ float zsc[Kk];
    __shared__ int   zidx[Kk];
    __shared__ float zsh[Kk][Ee];
    __shared__ float znorm[Kk];
    __shared__ float red[4][Kk];
    __shared__ float rules[Kk];

    int tid = threadIdx.x;
    int wv = tid >> 6, lane = tid & 63;

    if (wv == 0) {   // single-wave top-K, jax-stable ties (lowest index wins)
        float v[Nn / 64];
#pragma unroll
        for (int i = 0; i < Nn / 64; ++i) v[i] = sp[i * 64 + lane];
        for (int k = 0; k < Kk; ++k) {
            float best = -INFINITY; int bidx = 0;
#pragma unroll
            for (int i = 0; i < Nn / 64; ++i)
                if (v[i] > best) { best = v[i]; bidx = i * 64 + lane; }
#pragma unroll
            for (int m = 1; m < 64; m <<= 1) {
                float ov = __shfl_xor(best, m);
                int oi = __shfl_xor(bidx, m);
                if (ov > best || (ov == best && oi < bidx)) { best = ov; bidx = oi; }
            }
            if (lane == 0) { zsc[k] = best; zidx[k] = bidx; }
            if ((bidx & 63) == lane) {
                int slot = bidx >> 6;
#pragma unroll
                for (int i = 0; i < Nn / 64; ++i)
                    if (i == slot) v[i] = -INFINITY;
            }
        }
    }
    __syncthreads();
    for (int idx = tid; idx < Kk * Ee; idx += 256) {
        int k = idx >> 7, e = idx & 127;
        zsh[k][e] = ent[((size_t)b * Nn + zidx[k]) * Ee + e];
    }
    __syncthreads();
    if (tid < Kk) {
        float s = 0.f;
        for (int e = 0; e < Ee; ++e) { float v = zsh[tid][e]; s += v * v; }
        znorm[tid] = s;
    }
    __syncthreads();

    int f = fc * S2F + tid;
    const float* fp = factX + ((size_t)b * Ff + f) * Ee;
    float acc[Kk];
#pragma unroll
    for (int k = 0; k < Kk; ++k) acc[k] = 0.f;
    float nf = 0.f;
#pragma unroll 4
    for (int e0 = 0; e0 < Ee; e0 += 4) {
        float4 v = *(const float4*)(fp + e0);
        nf += v.x * v.x + v.y * v.y + v.z * v.z + v.w * v.w;
#pragma unroll
        for (int k = 0; k < Kk; ++k) {
            float4 z = *(const float4*)&zsh[k][e0];
            acc[k] += z.x * v.x + z.y * v.y + z.z * v.z + z.w * v.w;
        }
    }
    float base = s2b[f] - 0.5f * nf;   // -INF for invalid facts
    float sc[Kk];
#pragma unroll
    for (int k = 0; k < Kk; ++k) sc[k] = base + acc[k] - 0.5f * znorm[k];
    for (int o = 32; o; o >>= 1)
#pragma unroll
        for (int k = 0; k < Kk; ++k) sc[k] = fmaxf(sc[k], __shfl_down(sc[k], o));
    if ((tid & 63) == 0)
#pragma unroll
        for (int k = 0; k < Kk; ++k) red[wv][k] = sc[k];
    __syncthreads();
    if (tid < Kk) {
        float m = fmaxf(fmaxf(red[0][tid], red[1][tid]), fmaxf(red[2][tid], red[3][tid]));
        // max_f min(exp(s_f), z) == min(exp(max_f s_f), z)
        rules[tid] = fminf(expf(m), zsc[tid]);
    }
    __syncthreads();
    if (tid == 0) {
        float g = rules[0];
#pragma unroll
        for (int k = 1; k < Kk; ++k) g = fmaxf(g, rules[k]);
        atomic_fmax_pos(out + b, g);   // ONE atomic per block
    }
}

extern "C" void kernel_launch(void* const* d_in, const int* in_sizes, int n_in,
                              void* d_out, int out_size, void* d_ws, size_t ws_size,
                              hipStream_t stream) {
    const float* rel  = (const float*)d_in[0];
    const float* arg1 = (const float*)d_in[1];
    const float* arg2 = (const float*)d_in[2];
    const float* frel = (const float*)d_in[3];
    const float* fa1  = (const float*)d_in[4];
    const float* fa2  = (const float*)d_in[5];
    const float* ent  = (const float*)d_in[6];
    const float* hopW = (const float*)d_in[7];
    const float* hopb = (const float*)d_in[8];
    const int* nb_facts    = (const int*)d_in[9];
    const int* nb_entities = (const int*)d_in[10];
    float* out = (float*)d_out;

    float* ws = (float*)d_ws;
    size_t off = 0;
    float* c0       = ws + off; off += (size_t)Bb * Ff;
    float* c1       = ws + off; off += (size_t)Bb * Ff;
    float* s2b0     = ws + off; off += (size_t)Bb * Ff;
    float* s2b1     = ws + off; off += (size_t)Bb * Ff;
    float* sp0      = ws + off; off += (size_t)Bb * Nn;
    float* sp1      = ws + off; off += (size_t)Bb * Nn;
    float* ent_norm = ws + off; off += (size_t)Bb * Nn;
    off = (off + 7) & ~(size_t)7;   // 32B-align the split tensors
    unsigned short* B0 = (unsigned short*)(ws + off); off += (size_t)Bb * 16 * Ff * 8;
    unsigned short* B1 = (unsigned short*)(ws + off); off += (size_t)Bb * 16 * Ff * 8;

    hipMemsetAsync(d_out, 0, (size_t)out_size * sizeof(float), stream);
    k_pfe<<<dim3(128 + 4096 + Bb * Nn / 4), 256, 0, stream>>>(
        rel, arg1, arg2, frel, fa1, fa2, ent, hopW, hopb, nb_facts,
        B0, B1, ent_norm, c0, c1, s2b0, s2b1, out);
    k_spmax_mfma<<<dim3(512), 256, 0, stream>>>(ent, B0, B1, c0, c1, ent_norm,
                                                nb_entities, sp0, sp1);
    k_s2t<<<dim3(S2FC, Bb, 2), 256, 0, stream>>>(ent, fa1, fa2, s2b0, s2b1,
                                                 sp0, sp1, out);
}